// Round 1
// baseline (942.161 us; speedup 1.0000x reference)
//
#include <hip/hip_runtime.h>
#include <math.h>

// CoreAttention  B=2 S=2048 H=16 D=64 — flash-style fused attention, R1.
//
// R1 theory: previous version latency-bound (1.41 TB/s, MfmaUtil 7.7%,
// VALUBusy 19%): 32 scalar bias/mask dword loads per lane per tile with zero
// prefetch distance, plus 32 ds_write_u16/thread LDS scatter (2.6e7 bank
// conflicts). Changes:
//  * scores computed TRANSPOSED (S^T = K*Q^T): C-frag fast axis (quad*4+r)
//    becomes the key dim -> bias = 4x float4, mask = 4x int4 per lane/tile,
//    softmax row-reduce = 2 shfls (was 32), epilogue = float4 stores.
//  * PV also transposed (O^T = V^T*P^T): same Vt reads, vectorized P via
//    4x ds_write_b64 (was 16x ds_write_u16).
//  * register prefetch pipeline (T14): K/V/bias/mask for tile t+1 issued
//    mid-compute of tile t; consumed after the barriers next iteration.
//  * V^T staged via 4x4 block transpose: 4x ds_write_b64 (was 16x u16).
//  * XCD swizzle: all 32 q-tiles of one (b,h) on one XCD -> 1MB K/V slice
//    L2-resident; bias/mask loads + out stores nontemporal to protect it.

namespace {
constexpr int Bn = 2, Sn = 2048, Hn = 16, Dn = 64;
constexpr int QT = 64;          // q rows per block (4 waves x 16)
constexpr int KT = 64;          // keys per tile
constexpr int NT = Sn / KT;     // 32 tiles
constexpr int ST = 72;          // LDS row stride in f16 (pad 64->72)

typedef _Float16 f16x8 __attribute__((ext_vector_type(8)));
typedef _Float16 f16x4 __attribute__((ext_vector_type(4)));
typedef float    f32x4 __attribute__((ext_vector_type(4)));
typedef int      i32x4 __attribute__((ext_vector_type(4)));
}

__global__ __launch_bounds__(256, 4)
void core_attn_kernel(const float* __restrict__ Q,
                      const float* __restrict__ K,
                      const float* __restrict__ V,
                      const float* __restrict__ Bias,
                      const int*   __restrict__ Mask,
                      float* __restrict__ Out)
{
    // XCD-aware remap: dispatch round-robins linear id across 8 XCDs; group
    // the 32 q-tiles sharing one (b,h) (same K/V slice) onto one XCD.
    const int p  = blockIdx.x + 32 * (blockIdx.y + 16 * blockIdx.z);
    const int sl = p >> 3;
    const int g  = (p & 7) + 8 * (sl >> 5);   // (b,h) group 0..31
    const int qt = sl & 31;
    const int h  = g & 15;
    const int b  = g >> 4;
    const int q0 = qt * QT;

    const int tid  = threadIdx.x;
    const int wave = tid >> 6;
    const int lane = tid & 63;
    const int c    = lane & 15;
    const int quad = lane >> 4;

    __shared__ __align__(16) _Float16 Khi[KT * ST];
    __shared__ __align__(16) _Float16 Klo[KT * ST];
    __shared__ __align__(16) _Float16 Vt [Dn * ST];     // Vt[d][key]
    __shared__ __align__(16) _Float16 Pl [4][16 * ST];  // per-wave P[q][key]

    const int qrow = q0 + wave * 16 + c;   // this lane's q row (B-frag n, C col)

    // ---- Q fragments (B layout: n=lane&15=q, k=quad*8+j), scaled by 8, hi/lo
    f16x8 qhi[2], qlo[2];
    {
        const float* qp = Q + ((size_t)((b * Sn + qrow) * Hn + h)) * Dn + quad * 8;
        #pragma unroll
        for (int kc = 0; kc < 2; ++kc) {
            f32x4 v0 = *(const f32x4*)(qp + kc * 32);
            f32x4 v1 = *(const f32x4*)(qp + kc * 32 + 4);
            float buf[8] = {v0[0], v0[1], v0[2], v0[3], v1[0], v1[1], v1[2], v1[3]};
            #pragma unroll
            for (int j = 0; j < 8; ++j) {
                float f = buf[j] * 8.0f;
                _Float16 hi = (_Float16)f;
                qhi[kc][j] = hi;
                qlo[kc][j] = (_Float16)(f - (float)hi);
            }
        }
    }

    // per-lane bias/mask bases: row = qrow, fast axis = key (quad*4 + r)
    const float* bias_base = Bias + ((size_t)(b * Hn + h) * Sn + qrow) * Sn + quad * 4;
    const int*   mask_base = Mask + ((size_t)b * Sn + qrow) * Sn + quad * 4;

    // staging maps
    const int ksrow = tid >> 2;            // K: row 0..63, 16-wide d segment
    const int kdseg = (tid & 3) * 16;
    const float* kbase = K + ((size_t)((b * Sn + ksrow) * Hn + h)) * Dn + kdseg;
    const int vkq = tid >> 4;              // V: 4x4 block (keys vkq*4.., d vdq..)
    const int vdq = (tid & 15) * 4;
    const float* vbase = V + ((size_t)((b * Sn + vkq * 4) * Hn + h)) * Dn + vdq;

    f32x4 kreg[4], vreg[4], breg[4];
    i32x4 mreg[4];

    auto issue_kv = [&](int k0) {
        const float* kp = kbase + (size_t)k0 * (Hn * Dn);
        const float* vp = vbase + (size_t)k0 * (Hn * Dn);
        #pragma unroll
        for (int i = 0; i < 4; ++i) kreg[i] = *(const f32x4*)(kp + 4 * i);
        #pragma unroll
        for (int i = 0; i < 4; ++i) vreg[i] = *(const f32x4*)(vp + (size_t)i * (Hn * Dn));
    };
    auto issue_b = [&](int k0) {
        #pragma unroll
        for (int ct = 0; ct < 4; ++ct)
            breg[ct] = __builtin_nontemporal_load((const f32x4*)(bias_base + k0 + ct * 16));
    };
    auto issue_m = [&](int k0) {
        #pragma unroll
        for (int ct = 0; ct < 4; ++ct)
            mreg[ct] = __builtin_nontemporal_load((const i32x4*)(mask_base + k0 + ct * 16));
    };
    auto stage = [&]() {
        // K: hi/lo split, 4x ds_write_b128
        f16x8 khiv[2], klov[2];
        const float* kf = (const float*)kreg;
        #pragma unroll
        for (int j = 0; j < 16; ++j) {
            float f = kf[j];
            _Float16 hi = (_Float16)f;
            khiv[j >> 3][j & 7] = hi;
            klov[j >> 3][j & 7] = (_Float16)(f - (float)hi);
        }
        *(f16x8*)&Khi[ksrow * ST + kdseg]     = khiv[0];
        *(f16x8*)&Khi[ksrow * ST + kdseg + 8] = khiv[1];
        *(f16x8*)&Klo[ksrow * ST + kdseg]     = klov[0];
        *(f16x8*)&Klo[ksrow * ST + kdseg + 8] = klov[1];
        // V: 4x4 block transpose, 4x ds_write_b64
        #pragma unroll
        for (int j = 0; j < 4; ++j) {
            f16x4 w;
            #pragma unroll
            for (int i = 0; i < 4; ++i) w[i] = (_Float16)vreg[i][j];
            *(f16x4*)&Vt[(vdq + j) * ST + vkq * 4] = w;
        }
    };

    f32x4 Oa[4];
    #pragma unroll
    for (int td = 0; td < 4; ++td) Oa[td] = (f32x4){0.f, 0.f, 0.f, 0.f};
    float m_i = -INFINITY, l_i = 0.0f;

    issue_kv(0);
    issue_b(0);
    issue_m(0);
    stage();   // waits K/V only (bias/mask stay in flight)

    for (int t = 0; t < NT; ++t) {
        __syncthreads();                    // stage(t) visible
        const int k0n = (t + 1) * KT;

        // ---- S^T = K*Q^T; C layout: row = key (quad*4+r), col = q (c).
        //      bias preloaded in regs as C-operand init.
        f32x4 acc[4];
        #pragma unroll
        for (int ct = 0; ct < 4; ++ct) acc[ct] = breg[ct];
        if (t + 1 < NT) issue_b(k0n);       // bias(t+1): ~full-iteration distance

        #pragma unroll
        for (int ct = 0; ct < 4; ++ct) {
            #pragma unroll
            for (int kc = 0; kc < 2; ++kc) {
                f16x8 kh = *(const f16x8*)&Khi[(ct * 16 + c) * ST + kc * 32 + quad * 8];
                f16x8 kl = *(const f16x8*)&Klo[(ct * 16 + c) * ST + kc * 32 + quad * 8];
                acc[ct] = __builtin_amdgcn_mfma_f32_16x16x32_f16(kh, qhi[kc], acc[ct], 0, 0, 0);
                acc[ct] = __builtin_amdgcn_mfma_f32_16x16x32_f16(kh, qlo[kc], acc[ct], 0, 0, 0);
                acc[ct] = __builtin_amdgcn_mfma_f32_16x16x32_f16(kl, qhi[kc], acc[ct], 0, 0, 0);
            }
        }

        float sc[4][4];
        #pragma unroll
        for (int ct = 0; ct < 4; ++ct) {
            #pragma unroll
            for (int r = 0; r < 4; ++r)
                sc[ct][r] = mreg[ct][r] ? 0.0f : acc[ct][r];
        }
        if (t + 1 < NT) { issue_m(k0n); issue_kv(k0n); }

        // ---- online softmax: lane owns q=c; 16 keys in-register, 2 shfls
        float mt = sc[0][0];
        #pragma unroll
        for (int ct = 0; ct < 4; ++ct) {
            #pragma unroll
            for (int r = 0; r < 4; ++r) mt = fmaxf(mt, sc[ct][r]);
        }
        mt = fmaxf(mt, __shfl_xor(mt, 16, 64));
        mt = fmaxf(mt, __shfl_xor(mt, 32, 64));
        float mn = fmaxf(m_i, mt);
        float alpha = __expf(m_i - mn);
        m_i = mn;
        float rs = 0.0f;
        #pragma unroll
        for (int ct = 0; ct < 4; ++ct) {
            #pragma unroll
            for (int r = 0; r < 4; ++r) {
                float pe = __expf(sc[ct][r] - mn);
                sc[ct][r] = pe;
                rs += pe;
            }
        }
        rs += __shfl_xor(rs, 16, 64);
        rs += __shfl_xor(rs, 32, 64);
        l_i = l_i * alpha + rs;
        #pragma unroll
        for (int td = 0; td < 4; ++td) {
            #pragma unroll
            for (int r = 0; r < 4; ++r) Oa[td][r] *= alpha;
        }

        // ---- P^T (C layout) -> Pl[q][key] -> B frag (per-wave region; DS
        //      ops are in-order within a wave, no barrier needed)
        #pragma unroll
        for (int ct = 0; ct < 4; ++ct) {
            f16x4 w;
            #pragma unroll
            for (int r = 0; r < 4; ++r) w[r] = (_Float16)sc[ct][r];
            *(f16x4*)&Pl[wave][c * ST + ct * 16 + quad * 4] = w;
        }
        f16x8 pf[2];
        #pragma unroll
        for (int kc = 0; kc < 2; ++kc)
            pf[kc] = *(const f16x8*)&Pl[wave][c * ST + kc * 32 + quad * 8];

        // ---- O^T += V^T * P^T  (A = Vt frag m=d, B = P frag n=q)
        #pragma unroll
        for (int td = 0; td < 4; ++td) {
            #pragma unroll
            for (int kc = 0; kc < 2; ++kc) {
                f16x8 vf = *(const f16x8*)&Vt[(td * 16 + c) * ST + kc * 32 + quad * 8];
                Oa[td] = __builtin_amdgcn_mfma_f32_16x16x32_f16(vf, pf[kc], Oa[td], 0, 0, 0);
            }
        }

        if (t + 1 < NT) {
            __syncthreads();   // all waves done reading LDS(t)
            stage();           // write tile t+1 (consumes kreg/vreg)
        }
    }

    // ---- epilogue: lane holds q=c, d = td*16 + quad*4 + r -> float4 stores
    const float inv = 1.0f / l_i;
    float* op = Out + ((size_t)(b * Sn + qrow)) * (Hn * Dn) + h * Dn + quad * 4;
    #pragma unroll
    for (int td = 0; td < 4; ++td) {
        f32x4 o;
        #pragma unroll
        for (int r = 0; r < 4; ++r) o[r] = Oa[td][r] * inv;
        __builtin_nontemporal_store(o, (f32x4*)(op + td * 16));
    }
}

extern "C" void kernel_launch(void* const* d_in, const int* in_sizes, int n_in,
                              void* d_out, int out_size, void* d_ws, size_t ws_size,
                              hipStream_t stream) {
    const float* q    = (const float*)d_in[0];
    const float* k    = (const float*)d_in[1];
    const float* v    = (const float*)d_in[2];
    const float* bias = (const float*)d_in[3];
    const int*   mask = (const int*)d_in[4];
    float* out = (float*)d_out;

    dim3 grid(Sn / QT, Hn, Bn);   // (32, 16, 2)
    core_attn_kernel<<<grid, 256, 0, stream>>>(q, k, v, bias, mask, out);
}

// Round 2
// 910.299 us; speedup vs baseline: 1.0350x; 1.0350x over previous
//
#include <hip/hip_runtime.h>
#include <math.h>

// CoreAttention  B=2 S=2048 H=16 D=64 — flash-style fused attention, R2.
//
// R1 post-mortem: VGPR_Count=64 proved the compiler SANK all register
// prefetches to their use sites (64 regs of prefetch buffers can't be live in
// a 64-reg allocation) -> every iteration serially exposed ~900cy of HBM
// latency on the bias stream. Also: nontemporal Out stores tripled
// WRITE_SIZE (16->48MB, partial-line write-through) and nontemporal mask
// loads defeated its 16x L3 reuse across heads (+84MB FETCH).
//
// R2 changes (isolating the prefetch variable):
//  * pin bias+mask prefetch issues with __builtin_amdgcn_sched_barrier(0)
//    so the loads stay ~1 iteration ahead of consumption (HBM-cold streams).
//    K/V left unpinned: L2-resident via XCD swizzle, short exposure.
//  * nontemporal kept ONLY on bias (read-once); removed from mask and Out.
// Validation signal: VGPR_Count should rise to ~115-130.

namespace {
constexpr int Bn = 2, Sn = 2048, Hn = 16, Dn = 64;
constexpr int QT = 64;          // q rows per block (4 waves x 16)
constexpr int KT = 64;          // keys per tile
constexpr int NT = Sn / KT;     // 32 tiles
constexpr int ST = 72;          // LDS row stride in f16 (pad 64->72)

typedef _Float16 f16x8 __attribute__((ext_vector_type(8)));
typedef _Float16 f16x4 __attribute__((ext_vector_type(4)));
typedef float    f32x4 __attribute__((ext_vector_type(4)));
typedef int      i32x4 __attribute__((ext_vector_type(4)));
}

__global__ __launch_bounds__(256, 4)
void core_attn_kernel(const float* __restrict__ Q,
                      const float* __restrict__ K,
                      const float* __restrict__ V,
                      const float* __restrict__ Bias,
                      const int*   __restrict__ Mask,
                      float* __restrict__ Out)
{
    // XCD-aware remap: group the 32 q-tiles sharing one (b,h) K/V slice on
    // one XCD (1MB slice stays L2-resident).
    const int p  = blockIdx.x + 32 * (blockIdx.y + 16 * blockIdx.z);
    const int sl = p >> 3;
    const int g  = (p & 7) + 8 * (sl >> 5);   // (b,h) group 0..31
    const int qt = sl & 31;
    const int h  = g & 15;
    const int b  = g >> 4;
    const int q0 = qt * QT;

    const int tid  = threadIdx.x;
    const int wave = tid >> 6;
    const int lane = tid & 63;
    const int c    = lane & 15;
    const int quad = lane >> 4;

    __shared__ __align__(16) _Float16 Khi[KT * ST];
    __shared__ __align__(16) _Float16 Klo[KT * ST];
    __shared__ __align__(16) _Float16 Vt [Dn * ST];     // Vt[d][key]
    __shared__ __align__(16) _Float16 Pl [4][16 * ST];  // per-wave P[q][key]

    const int qrow = q0 + wave * 16 + c;   // this lane's q row (B-frag n, C col)

    // ---- Q fragments (B layout: n=lane&15=q, k=quad*8+j), scaled by 8, hi/lo
    f16x8 qhi[2], qlo[2];
    {
        const float* qp = Q + ((size_t)((b * Sn + qrow) * Hn + h)) * Dn + quad * 8;
        #pragma unroll
        for (int kc = 0; kc < 2; ++kc) {
            f32x4 v0 = *(const f32x4*)(qp + kc * 32);
            f32x4 v1 = *(const f32x4*)(qp + kc * 32 + 4);
            float buf[8] = {v0[0], v0[1], v0[2], v0[3], v1[0], v1[1], v1[2], v1[3]};
            #pragma unroll
            for (int j = 0; j < 8; ++j) {
                float f = buf[j] * 8.0f;
                _Float16 hi = (_Float16)f;
                qhi[kc][j] = hi;
                qlo[kc][j] = (_Float16)(f - (float)hi);
            }
        }
    }

    // per-lane bias/mask bases: row = qrow, fast axis = key (quad*4 + r)
    const float* bias_base = Bias + ((size_t)(b * Hn + h) * Sn + qrow) * Sn + quad * 4;
    const int*   mask_base = Mask + ((size_t)b * Sn + qrow) * Sn + quad * 4;

    // staging maps
    const int ksrow = tid >> 2;            // K: row 0..63, 16-wide d segment
    const int kdseg = (tid & 3) * 16;
    const float* kbase = K + ((size_t)((b * Sn + ksrow) * Hn + h)) * Dn + kdseg;
    const int vkq = tid >> 4;              // V: 4x4 block (keys vkq*4.., d vdq..)
    const int vdq = (tid & 15) * 4;
    const float* vbase = V + ((size_t)((b * Sn + vkq * 4) * Hn + h)) * Dn + vdq;

    f32x4 kreg[4], vreg[4], breg[4];
    i32x4 mreg[4];

    auto issue_kv = [&](int k0) {
        const float* kp = kbase + (size_t)k0 * (Hn * Dn);
        const float* vp = vbase + (size_t)k0 * (Hn * Dn);
        #pragma unroll
        for (int i = 0; i < 4; ++i) kreg[i] = *(const f32x4*)(kp + 4 * i);
        #pragma unroll
        for (int i = 0; i < 4; ++i) vreg[i] = *(const f32x4*)(vp + (size_t)i * (Hn * Dn));
    };
    auto issue_b = [&](int k0) {
        #pragma unroll
        for (int ct = 0; ct < 4; ++ct)
            breg[ct] = __builtin_nontemporal_load((const f32x4*)(bias_base + k0 + ct * 16));
    };
    auto issue_m = [&](int k0) {
        #pragma unroll
        for (int ct = 0; ct < 4; ++ct)
            mreg[ct] = *(const i32x4*)(mask_base + k0 + ct * 16);
    };
    auto stage = [&]() {
        // K: hi/lo split, 4x ds_write_b128
        f16x8 khiv[2], klov[2];
        const float* kf = (const float*)kreg;
        #pragma unroll
        for (int j = 0; j < 16; ++j) {
            float f = kf[j];
            _Float16 hi = (_Float16)f;
            khiv[j >> 3][j & 7] = hi;
            klov[j >> 3][j & 7] = (_Float16)(f - (float)hi);
        }
        *(f16x8*)&Khi[ksrow * ST + kdseg]     = khiv[0];
        *(f16x8*)&Khi[ksrow * ST + kdseg + 8] = khiv[1];
        *(f16x8*)&Klo[ksrow * ST + kdseg]     = klov[0];
        *(f16x8*)&Klo[ksrow * ST + kdseg + 8] = klov[1];
        // V: 4x4 block transpose, 4x ds_write_b64
        #pragma unroll
        for (int j = 0; j < 4; ++j) {
            f16x4 w;
            #pragma unroll
            for (int i = 0; i < 4; ++i) w[i] = (_Float16)vreg[i][j];
            *(f16x4*)&Vt[(vdq + j) * ST + vkq * 4] = w;
        }
    };

    f32x4 Oa[4];
    #pragma unroll
    for (int td = 0; td < 4; ++td) Oa[td] = (f32x4){0.f, 0.f, 0.f, 0.f};
    float m_i = -INFINITY, l_i = 0.0f;

    issue_b(0);
    issue_m(0);
    __builtin_amdgcn_sched_barrier(0);   // pin: bias/mask(0) issued before staging waits
    issue_kv(0);
    stage();   // waits K/V only (bias/mask stay in flight)

    for (int t = 0; t < NT; ++t) {
        __syncthreads();                    // stage(t) visible
        const int k0n = (t + 1) * KT;

        // ---- S^T = K*Q^T; C layout: row = key (quad*4+r), col = q (c).
        //      bias preloaded in regs as C-operand init.
        f32x4 acc[4];
        #pragma unroll
        for (int ct = 0; ct < 4; ++ct) acc[ct] = breg[ct];

        #pragma unroll
        for (int ct = 0; ct < 4; ++ct) {
            #pragma unroll
            for (int kc = 0; kc < 2; ++kc) {
                f16x8 kh = *(const f16x8*)&Khi[(ct * 16 + c) * ST + kc * 32 + quad * 8];
                f16x8 kl = *(const f16x8*)&Klo[(ct * 16 + c) * ST + kc * 32 + quad * 8];
                acc[ct] = __builtin_amdgcn_mfma_f32_16x16x32_f16(kh, qhi[kc], acc[ct], 0, 0, 0);
                acc[ct] = __builtin_amdgcn_mfma_f32_16x16x32_f16(kh, qlo[kc], acc[ct], 0, 0, 0);
                acc[ct] = __builtin_amdgcn_mfma_f32_16x16x32_f16(kl, qhi[kc], acc[ct], 0, 0, 0);
            }
        }

        float sc[4][4];
        #pragma unroll
        for (int ct = 0; ct < 4; ++ct) {
            #pragma unroll
            for (int r = 0; r < 4; ++r)
                sc[ct][r] = mreg[ct][r] ? 0.0f : acc[ct][r];
        }

        // ---- prefetch cluster for tile t+1: old breg/mreg are now consumed.
        //      sched_barrier(0) pins the issues here (~1 iter ahead of use) —
        //      without it the compiler sinks them to their uses (R1 lesson).
        if (t + 1 < NT) {
            issue_b(k0n);
            issue_m(k0n);
            __builtin_amdgcn_sched_barrier(0);
            issue_kv(k0n);   // unpinned: L2-resident, consumed at stage() below
        }

        // ---- online softmax: lane owns q=c; 16 keys in-register, 2 shfls
        float mt = sc[0][0];
        #pragma unroll
        for (int ct = 0; ct < 4; ++ct) {
            #pragma unroll
            for (int r = 0; r < 4; ++r) mt = fmaxf(mt, sc[ct][r]);
        }
        mt = fmaxf(mt, __shfl_xor(mt, 16, 64));
        mt = fmaxf(mt, __shfl_xor(mt, 32, 64));
        float mn = fmaxf(m_i, mt);
        float alpha = __expf(m_i - mn);
        m_i = mn;
        float rs = 0.0f;
        #pragma unroll
        for (int ct = 0; ct < 4; ++ct) {
            #pragma unroll
            for (int r = 0; r < 4; ++r) {
                float pe = __expf(sc[ct][r] - mn);
                sc[ct][r] = pe;
                rs += pe;
            }
        }
        rs += __shfl_xor(rs, 16, 64);
        rs += __shfl_xor(rs, 32, 64);
        l_i = l_i * alpha + rs;
        #pragma unroll
        for (int td = 0; td < 4; ++td) {
            #pragma unroll
            for (int r = 0; r < 4; ++r) Oa[td][r] *= alpha;
        }

        // ---- P^T (C layout) -> Pl[q][key] -> B frag (per-wave region; DS
        //      ops are in-order within a wave, no barrier needed)
        #pragma unroll
        for (int ct = 0; ct < 4; ++ct) {
            f16x4 w;
            #pragma unroll
            for (int r = 0; r < 4; ++r) w[r] = (_Float16)sc[ct][r];
            *(f16x4*)&Pl[wave][c * ST + ct * 16 + quad * 4] = w;
        }
        f16x8 pf[2];
        #pragma unroll
        for (int kc = 0; kc < 2; ++kc)
            pf[kc] = *(const f16x8*)&Pl[wave][c * ST + kc * 32 + quad * 8];

        // ---- O^T += V^T * P^T  (A = Vt frag m=d, B = P frag n=q)
        #pragma unroll
        for (int td = 0; td < 4; ++td) {
            #pragma unroll
            for (int kc = 0; kc < 2; ++kc) {
                f16x8 vf = *(const f16x8*)&Vt[(td * 16 + c) * ST + kc * 32 + quad * 8];
                Oa[td] = __builtin_amdgcn_mfma_f32_16x16x32_f16(vf, pf[kc], Oa[td], 0, 0, 0);
            }
        }

        if (t + 1 < NT) {
            __syncthreads();   // all waves done reading LDS(t)
            stage();           // write tile t+1 (consumes kreg/vreg)
        }
    }

    // ---- epilogue: lane holds q=c, d = td*16 + quad*4 + r -> float4 stores
    const float inv = 1.0f / l_i;
    float* op = Out + ((size_t)(b * Sn + qrow)) * (Hn * Dn) + h * Dn + quad * 4;
    #pragma unroll
    for (int td = 0; td < 4; ++td) {
        f32x4 o;
        #pragma unroll
        for (int r = 0; r < 4; ++r) o[r] = Oa[td][r] * inv;
        *(f32x4*)(op + td * 16) = o;
    }
}

extern "C" void kernel_launch(void* const* d_in, const int* in_sizes, int n_in,
                              void* d_out, int out_size, void* d_ws, size_t ws_size,
                              hipStream_t stream) {
    const float* q    = (const float*)d_in[0];
    const float* k    = (const float*)d_in[1];
    const float* v    = (const float*)d_in[2];
    const float* bias = (const float*)d_in[3];
    const int*   mask = (const int*)d_in[4];
    float* out = (float*)d_out;

    dim3 grid(Sn / QT, Hn, Bn);   // (32, 16, 2)
    core_attn_kernel<<<grid, 256, 0, stream>>>(q, k, v, bias, mask, out);
}